// Round 12
// baseline (286.925 us; speedup 1.0000x reference)
//
#include <hip/hip_runtime.h>
#include <cmath>

#define BB 4
#define TT 2048
#define CC 1024
#define HH 16
#define DD 64
#define MM (BB*TT)   // 8192

typedef _Float16 f16x8 __attribute__((ext_vector_type(8)));
typedef _Float16 f16x4 __attribute__((ext_vector_type(4)));
typedef _Float16 f16x2 __attribute__((ext_vector_type(2)));
typedef float f32x4 __attribute__((ext_vector_type(4)));
typedef unsigned short ushort_t;

// legacy K=16 f16 MFMA: spelled WITHOUT underscore before f16 (pre-gfx950
// naming; compiler fix-it verified R7)
#define MFMA16(a,b,c) __builtin_amdgcn_mfma_f32_16x16x16f16(a,b,c,0,0,0)

__device__ __forceinline__ unsigned short f2h(float f) {
    _Float16 h = (_Float16)f;
    return __builtin_bit_cast(unsigned short, h);
}

// packed f32x2 -> f16x2 (v_cvt_pkrtz_f16_f32); builtin returns __fp16x2,
// bit-cast to our _Float16x2 (identical layout)
__device__ __forceinline__ f16x2 cvt_pk(float a, float b) {
    return __builtin_bit_cast(f16x2, __builtin_amdgcn_cvt_pkrtz(a, b));
}

// async global->LDS, 16 bytes per lane (lane i -> base + i*16).
__device__ __forceinline__ void gld16(const void* gsrc, void* ldst) {
    void* g = const_cast<void*>(gsrc);
    __builtin_amdgcn_global_load_lds(
        (__attribute__((address_space(1))) void*)g,
        (__attribute__((address_space(3))) void*)ldst,
        16, 0, 0);
}

// ---------------------------------------------------------------------------
// prep: fp32 -> f16 (packed x4)
// ---------------------------------------------------------------------------
__global__ __launch_bounds__(256)
void cvt4_kernel(const float* __restrict__ in, ushort_t* __restrict__ out, long n4) {
    long i = (long)blockIdx.x * blockDim.x + threadIdx.x;
    if (i >= n4) return;
    float4 v = ((const float4*)in)[i];
    ushort4 o;
    o.x = f2h(v.x); o.y = f2h(v.y); o.z = f2h(v.z); o.w = f2h(v.w);
    ((ushort4*)out)[i] = o;
}

// ---------------------------------------------------------------------------
// prep: transpose + convert BOTH weights in one launch:
// bx<96 -> w_attn [1024][3072]; else w_proj [1024][1024]. out[N][K] f16.
// ---------------------------------------------------------------------------
__global__ __launch_bounds__(256)
void trcvt2_kernel(const float* __restrict__ wa, const float* __restrict__ wp,
                   ushort_t* __restrict__ oa, ushort_t* __restrict__ op) {
    __shared__ float T[32][33];
    const int K = 1024;
    const float* in;
    ushort_t* out;
    int N, n0;
    if (blockIdx.x < 96) { in = wa; out = oa; N = 3072; n0 = blockIdx.x * 32; }
    else                 { in = wp; out = op; N = 1024; n0 = (blockIdx.x - 96) * 32; }
    const int tx = threadIdx.x & 31;
    const int ty = threadIdx.x >> 5;
    const int k0 = blockIdx.y * 32;
    #pragma unroll
    for (int i = 0; i < 4; ++i)
        T[ty + i * 8][tx] = in[(size_t)(k0 + ty + i * 8) * N + n0 + tx];
    __syncthreads();
    #pragma unroll
    for (int i = 0; i < 4; ++i)
        out[(size_t)(n0 + ty + i * 8) * K + k0 + tx] = f2h(T[tx][ty + i * 8]);
}

// ---------------------------------------------------------------------------
// GEMM1, R19: fine-phase counted-vmcnt schedule (m201 family) in a provably
// race-free 3-buffer/BK=32 variant, 256x256 tile, 8 waves (2m x 4n), wave
// owns 128x64. Grid 32x12 = 384 blocks, 96KB dyn LDS, 1 block/CU.
// Per K-tile t (buf ct=t%3): 4 quadrant-phases, each
//   { frag ds_reads (A or B subset; regs reused across phases) ||
//     stage 1 half-tile of K-tile t+2 into buf (t+2)%3 (1 gld16/wave)
//     -> raw s_barrier -> setprio(1) 8 MFMA setprio(0) -> raw s_barrier }
// vmcnt(4) at q3 (leaves only this iter's 4 stages in flight -> K-tile t+1
// landed before any wave crosses into iter t+1). Race-freedom: stage target
// buf (t+2)%3 == buf (t-1)%3, whose readers all passed iter t-1's final
// barrier before any iter-t stage is issued; landing follows issue.
// T2 swizzle (rule #21, both-sides): subtile [16r x 32c f16] = 1KB = one
// wave-gld16; LDS dest linear; global source col ^= (lane>=32 ? 16 : 0)
// halves; read offset halves ^= (lrow&8 ? 16 : 0). Involution desk-checked.
// Epilogue: R17's coalesced per-wave LDS bounce, 2 chunks of 64 rows (8KB
// scratch/wave). q pre-scaled by 8*log2(e); v TRANSPOSED [B,H,D,T].
// ---------------------------------------------------------------------------
__global__ __launch_bounds__(512, 2)
void hgemm8_kernel(const ushort_t* __restrict__ A, const ushort_t* __restrict__ Bt,
                   const float* __restrict__ bias,
                   ushort_t* __restrict__ qh, ushort_t* __restrict__ kh,
                   ushort_t* __restrict__ vh)
{
    extern __shared__ ushort_t LDS[];     // 3 bufs x 16384 halves = 96KB

    const int tid  = threadIdx.x;
    const int lane = tid & 63;
    const int wid  = tid >> 6;            // 0..7
    const int wm   = wid >> 2;            // 0..1
    const int wn   = wid & 3;             // 0..3
    const int lrow = lane & 15;
    const int quad = lane >> 4;

    // XCD-chunked bijective swizzle (384 % 8 == 0), n-fast within chunk
    int bid = blockIdx.x;
    bid = (bid & 7) * 48 + (bid >> 3);
    const int m0 = (bid / 12) * 256;
    const int n0 = (bid % 12) * 256;

    // staging: wave stages subtile `wid` of each half-tile (128 rows x 32
    // cols f16 = 8 subtiles of [16][32]). lane L covers phys bytes L*16 of
    // the subtile; inverse-swizzled global source:
    const int rr = lane >> 2;                               // subtile row
    const int cc = ((lane & 3) * 8) ^ ((lane & 32) ? 16 : 0); // col halves
    const unsigned gA0 = (unsigned)(m0 +       wid * 16 + rr) * 1024 + cc;
    const unsigned gA1 = (unsigned)(m0 + 128 + wid * 16 + rr) * 1024 + cc;
    const unsigned gB0 = (unsigned)(n0 +       wid * 16 + rr) * 1024 + cc;
    const unsigned gB1 = (unsigned)(n0 + 128 + wid * 16 + rr) * 1024 + cc;

    // frag-read base offsets (halves), swizzled
    const int swz  = (lrow & 8) ? 16 : 0;
    const int rdA0 = wm * 4096 + lrow * 32 + ((quad * 8) ^ swz);
    const int rdB0 = 8192 + (wn >> 1) * 4096 +
                     ((wn & 1) * 64 + lrow) * 32 + ((quad * 8) ^ swz);

    f32x4 acc[8][4];
    const f32x4 z = {0.f, 0.f, 0.f, 0.f};
    #pragma unroll
    for (int im = 0; im < 8; ++im)
        #pragma unroll
        for (int in = 0; in < 4; ++in)
            acc[im][in] = z;

    // stage half-tile `hf` (0:A-h0 1:A-h1 2:B-h0 3:B-h1) of K-tile t2
    auto STAGE = [&](int t2, int hf) {
        ushort_t* dst = &LDS[(t2 % 3) * 16384 + ((hf >= 2) ? 8192 : 0) +
                             (hf & 1) * 4096 + wid * 512];
        const unsigned go = (hf == 0 ? gA0 : hf == 1 ? gA1 : hf == 2 ? gB0 : gB1)
                            + (unsigned)t2 * 32;
        gld16((hf >= 2 ? Bt : A) + go, dst);
    };

    f16x8 af[4], bf[4];

#define LDA_Q(QM) { _Pragma("unroll") \
    for (int mt = 0; mt < 4; ++mt) \
        af[mt] = *(const f16x8*)&LDS[ctb + rdA0 + ((QM) * 4 + mt) * 512]; }
#define LDB_J(JN) { bf[JN] = *(const f16x8*)&LDS[ctb + rdB0 + (JN) * 512]; }
#define DO_MFMA(QM, QN) { \
    __builtin_amdgcn_s_setprio(1); \
    _Pragma("unroll") \
    for (int mt = 0; mt < 4; ++mt) \
        _Pragma("unroll") \
        for (int nt = 0; nt < 2; ++nt) \
            acc[(QM) * 4 + mt][(QN) * 2 + nt] = \
                __builtin_amdgcn_mfma_f32_16x16x32_f16( \
                    af[mt], bf[(QN) * 2 + nt], acc[(QM) * 4 + mt][(QN) * 2 + nt], \
                    0, 0, 0); \
    __builtin_amdgcn_s_setprio(0); }

    // prologue: stage K-tiles 0 and 1 (8 gld16/wave); K-tile 0 landed
    #pragma unroll
    for (int hf = 0; hf < 4; ++hf) STAGE(0, hf);
    #pragma unroll
    for (int hf = 0; hf < 4; ++hf) STAGE(1, hf);
    asm volatile("s_waitcnt vmcnt(4)" ::: "memory");
    __builtin_amdgcn_s_barrier();

    for (int t = 0; t < 32; ++t) {
        const int ctb = (t % 3) * 16384;
        const bool st = (t < 30);
        // phase 0: quadrant (m0,n0); read A-half qm=0 + B frags 0,1
        LDA_Q(0); LDB_J(0); LDB_J(1);
        if (st) STAGE(t + 2, 0);
        __builtin_amdgcn_s_barrier();
        DO_MFMA(0, 0);
        __builtin_amdgcn_s_barrier();
        // phase 1: quadrant (m0,n1); read B frags 2,3
        LDB_J(2); LDB_J(3);
        if (st) STAGE(t + 2, 1);
        __builtin_amdgcn_s_barrier();
        DO_MFMA(0, 1);
        __builtin_amdgcn_s_barrier();
        // phase 2: quadrant (m1,n1); read A-half qm=1 (reuse bf 2,3)
        LDA_Q(1);
        if (st) STAGE(t + 2, 2);
        __builtin_amdgcn_s_barrier();
        DO_MFMA(1, 1);
        __builtin_amdgcn_s_barrier();
        // phase 3: quadrant (m1,n0); no reads (reuse af, bf 0,1)
        if (st) STAGE(t + 2, 3);
        if (t < 30) asm volatile("s_waitcnt vmcnt(4)" ::: "memory");
        else        asm volatile("s_waitcnt vmcnt(0)" ::: "memory");
        __builtin_amdgcn_s_barrier();
        DO_MFMA(1, 0);
        __builtin_amdgcn_s_barrier();
    }
#undef LDA_Q
#undef LDB_J
#undef DO_MFMA

    // epilogue: coalesced QKV via per-wave LDS bounce (LDS quiescent after
    // the loop's final barrier; waves use disjoint 8KB scratch regions),
    // two chunks of 64 t-rows each.
    ushort_t* scr = &LDS[wid * 4096];
    const int colw  = n0 + wn * 64;
    const int which = colw >> 10;
    const int hh    = (colw & 1023) >> 6;
    const int rowt  = m0 + wm * 128;
    const int b2    = rowt >> 11;
    const int t0w   = rowt & 2047;
    #pragma unroll
    for (int ch = 0; ch < 2; ++ch) {
        if (ch) asm volatile("s_waitcnt lgkmcnt(0)" ::: "memory"); // scr reads done
        if (which == 2) {
            // v: scr[d][t]; global 64 d-rows x 64 t-cols at t0w+ch*64
            #pragma unroll
            for (int mt = 0; mt < 4; ++mt)
                #pragma unroll
                for (int in = 0; in < 4; ++in) {
                    const float bv = bias[colw + in * 16 + lrow];
                    f16x4 pk;
                    #pragma unroll
                    for (int r = 0; r < 4; ++r)
                        pk[r] = (_Float16)(acc[ch * 4 + mt][in][r] + bv);
                    *(f16x4*)&scr[(in * 16 + lrow) * 64 + mt * 16 + quad * 4] = pk;
                }
            asm volatile("s_waitcnt lgkmcnt(0)" ::: "memory");
            ushort_t* base = vh + ((size_t)b2 * HH + hh) * DD * TT + t0w + ch * 64;
            #pragma unroll
            for (int it = 0; it < 8; ++it) {
                const int g  = it * 64 + lane;
                const int dd = g >> 3, c2 = (g & 7) * 8;
                *(uint4*)&base[(size_t)dd * TT + c2] = *(const uint4*)&scr[dd * 64 + c2];
            }
        } else {
            // q/k: scr[t][d]; global run contiguous 8KB
            const float sc = which ? 1.0f : 8.0f * 1.44269504088896f;
            #pragma unroll
            for (int mt = 0; mt < 4; ++mt)
                #pragma unroll
                for (int in = 0; in < 4; ++in) {
                    const float bv = bias[colw + in * 16 + lrow];
                    #pragma unroll
                    for (int r = 0; r < 4; ++r)
                        scr[(mt * 16 + quad * 4 + r) * 64 + in * 16 + lrow] =
                            f2h((acc[ch * 4 + mt][in][r] + bv) * sc);
                }
            asm volatile("s_waitcnt lgkmcnt(0)" ::: "memory");
            ushort_t* dstp = (which ? kh : qh) +
                             ((size_t)(b2 * HH + hh) * TT + t0w + ch * 64) * DD;
            #pragma unroll
            for (int it = 0; it < 8; ++it) {
                const int g = it * 64 + lane;
                *(uint4*)&dstp[g * 8] = *(const uint4*)&scr[g * 8];
            }
        }
    }
}

// ---------------------------------------------------------------------------
// f16 MFMA GEMM (GEMM2 only), R13/R18 core: BK=64, two [128][32] sub-blocks,
// 32KB LDS, XCD-chunked swizzle. fp32 out + bias.
// ---------------------------------------------------------------------------
template<int N>
__global__ __launch_bounds__(256)
void hgemm_kernel(const ushort_t* __restrict__ A, const ushort_t* __restrict__ Bt,
                  const float* __restrict__ bias, float* __restrict__ out)
{
    const int K = 1024;
    __shared__ ushort_t LDSU[16384];      // As: [0,8192) Bs: [8192,16384) halves

    const int tid  = threadIdx.x;
    const int lane = tid & 63;
    const int wave = tid >> 6;
    const int wm   = (wave & 1) * 64;
    const int wn   = (wave >> 1) * 64;
    const int lrow = lane & 15;
    const int quad = lane >> 4;

    const int gx  = gridDim.x;
    const int nwg = gx * gridDim.y;
    int bid = blockIdx.y * gx + blockIdx.x;
    bid = (bid & 7) * (nwg >> 3) + (bid >> 3);
    const int m0 = (bid / gx) * 128;
    const int n0 = (bid % gx) * 128;

    unsigned offA[4], offB[4];
    ushort_t* ldsA[4];
    ushort_t* ldsB[4];
    #pragma unroll
    for (int p = 0; p < 4; ++p) {
        const int d   = p * 256 + tid;
        const int blk = d >> 9;
        const int row = (d >> 2) & 127;
        const int c16 = d & 3;
        offA[p] = (unsigned)(m0 + row) * K + blk * 32 + c16 * 8;
        offB[p] = (unsigned)(n0 + row) * K + blk * 32 + c16 * 8;
        ldsA[p] = &LDSU[0]    + (p * 256 + wave * 64) * 8;
        ldsB[p] = &LDSU[8192] + (p * 256 + wave * 64) * 8;
    }

    f32x4 acc[4][4];
    const f32x4 z = {0.f, 0.f, 0.f, 0.f};
    #pragma unroll
    for (int mt = 0; mt < 4; ++mt)
        #pragma unroll
        for (int nt = 0; nt < 4; ++nt)
            acc[mt][nt] = z;

    for (int kk = 0; kk < K; kk += 64) {
        #pragma unroll
        for (int p = 0; p < 4; ++p) {
            gld16(&A[offA[p] + kk],  ldsA[p]);
            gld16(&Bt[offB[p] + kk], ldsB[p]);
        }
        __syncthreads();

        #pragma unroll
        for (int ks = 0; ks < 2; ++ks) {
            f16x8 af[4], bf[4];
            #pragma unroll
            for (int mt = 0; mt < 4; ++mt)
                af[mt] = *(const f16x8*)&LDSU[ks * 4096 + (wm + mt * 16 + lrow) * 32 + quad * 8];
            #pragma unroll
            for (int nt = 0; nt < 4; ++nt)
                bf[nt] = *(const f16x8*)&LDSU[8192 + ks * 4096 + (wn + nt * 16 + lrow) * 32 + quad * 8];
            #pragma unroll
            for (int mt = 0; mt < 4; ++mt)
                #pragma unroll
                for (int nt = 0; nt < 4; ++nt)
                    acc[mt][nt] = __builtin_amdgcn_mfma_f32_16x16x32_f16(
                        af[mt], bf[nt], acc[mt][nt], 0, 0, 0);
        }
        __syncthreads();
    }

    #pragma unroll
    for (int mt = 0; mt < 4; ++mt) {
        const int rbase = m0 + wm + mt * 16 + quad * 4;
        #pragma unroll
        for (int nt = 0; nt < 4; ++nt) {
            const int col = n0 + wn + nt * 16 + lrow;
            const float bv = bias[col];
            #pragma unroll
            for (int r = 0; r < 4; ++r)
                out[(size_t)(rbase + r) * N + col] = acc[mt][nt][r] + bv;
        }
    }
}

// ---------------------------------------------------------------------------
// MFMA flash attention, R16 structure (95us, best): 128-q-row blocks, 8
// waves, balanced pair (qtA=15-pr, qtB=pr), 34 iterations, grid 8x64 = 512
// blocks = exactly 2/CU. Double-buffered LDS one-barrier loop, S^T=K*Q^T
// swapped operands, in-lane softmax + 2 shuffles, tree max/sum, defer-max
// THR=8 (exp2 domain), cvt_pk P->f16, setprio, P^T C-layout = PV A-frag,
// reg prefetch of next K/V tile.
// qh,kh: f16 [B*H][T][D]; vh: f16 [B*H][D][T]; yh: f16 [B*T][C].
// ---------------------------------------------------------------------------
__global__ __launch_bounds__(512, 4)
void attn_mfma_kernel(const ushort_t* __restrict__ qh, const ushort_t* __restrict__ kh,
                      const ushort_t* __restrict__ vh, ushort_t* __restrict__ yh)
{
    __shared__ ushort_t Ks[2][64 * 72];   // [buf][key][d]
    __shared__ ushort_t Vs[2][64 * 72];   // [buf][d][key] (V transposed)

    const int pr   = blockIdx.x;          // pair index 0..7
    const int bh   = blockIdx.y;
    const int qtA  = 15 - pr;             // big tile first (128-row q-tiles)
    const int qtB  = pr;
    const int itA  = 2 * qtA + 2;         // phase-A k-iterations
    const int tid  = threadIdx.x;
    const int lane = tid & 63;
    const int w    = tid >> 6;            // 0..7
    const int lrow = lane & 15;
    const int quad = lane >> 4;

    const ushort_t* qbase = qh + (size_t)bh * TT * DD;
    const ushort_t* kbase = kh + (size_t)bh * TT * DD;
    const ushort_t* vbase = vh + (size_t)bh * DD * TT;
    const int b = bh >> 4, h = bh & 15;

    // staging: 512 threads x (1 K + 1 V) uint4; row ur (0..63), 16B chunk uc
    const int ur = tid >> 3;              // 0..63
    const int uc = (tid & 7) * 8;         // halves

    int q0w = qtA * 128 + w * 16;
    f16x8 aq0 = *(const f16x8*)&qbase[(size_t)(q0w + lrow) * DD + quad * 8];
    f16x8 aq1 = *(const f16x8*)&qbase[(size_t)(q0w + lrow) * DD + 32 + quad * 8];

    const f32x4 z = {0.f, 0.f, 0.f, 0.f};
    f32x4 o[4] = {z, z, z, z};
    float mi = -1e30f, li = 0.f;

    // tile 0 regs
    uint4 kr = *(const uint4*)&kbase[(size_t)ur * DD + uc];
    uint4 vr = *(const uint4*)&vbase[(size_t)ur * TT + uc];

    // prologue: publish tile 0 into buf0, prefetch tile 1 (kt=1 since itA>=18)
    *(uint4*)&Ks[0][ur * 72 + uc] = kr;
    *(uint4*)&Vs[0][ur * 72 + uc] = vr;
    kr = *(const uint4*)&kbase[(size_t)(64 + ur) * DD + uc];
    vr = *(const uint4*)&vbase[(size_t)ur * TT + 64 + uc];
    __syncthreads();

    for (int i = 0; i < 34; ++i) {
        const int cur = i & 1;
        if (i == itA) {
            // flush phase-A output; reset state for phase B
            #pragma unroll
            for (int r = 0; r < 4; ++r) {
                const float inv = 1.0f / __shfl(li, quad * 4 + r, 64);
                const int t = q0w + quad * 4 + r;
                #pragma unroll
                for (int dt = 0; dt < 4; ++dt)
                    yh[((size_t)b * TT + t) * CC + h * 64 + dt * 16 + lrow] =
                        f2h(o[dt][r] * inv);
            }
            q0w = qtB * 128 + w * 16;
            aq0 = *(const f16x8*)&qbase[(size_t)(q0w + lrow) * DD + quad * 8];
            aq1 = *(const f16x8*)&qbase[(size_t)(q0w + lrow) * DD + 32 + quad * 8];
            #pragma unroll
            for (int dt = 0; dt < 4; ++dt) o[dt] = z;
            mi = -1e30f; li = 0.f;
        }
        const int kt = (i < itA) ? i : i - itA;
        const int kt2 = kt * 64;
        // wave-uniform: skip tiles fully above the causal diagonal for this
        // wave's q-rows (min qg = q0w; all keys > q0w+15 -> all-masked)
        if (kt2 <= q0w + 15) {
            // S^T = K Q^T : C[row=key=quad*4+r][col=q=lrow]
            f32x4 sv[4];
            __builtin_amdgcn_s_setprio(1);
            #pragma unroll
            for (int c = 0; c < 4; ++c) {
                f16x8 ka = *(const f16x8*)&Ks[cur][(c * 16 + lrow) * 72 + quad * 8];
                f16x8 kb = *(const f16x8*)&Ks[cur][(c * 16 + lrow) * 72 + 32 + quad * 8];
                sv[c] = __builtin_amdgcn_mfma_f32_16x16x32_f16(ka, aq0, z, 0, 0, 0);
                sv[c] = __builtin_amdgcn_mfma_f32_16x16x32_f16(kb, aq1, sv[c], 0, 0, 0);
            }
            __builtin_amdgcn_s_setprio(0);

            // softmax: lane owns q-row qg; its 16 values are keys kt2+c*16+quad*4+r
            const int qg = q0w + lrow;
            if (kt2 + 63 > q0w) {         // partial-overlap tile: causal mask
                #pragma unroll
                for (int c = 0; c < 4; ++c)
                    #pragma unroll
                    for (int r = 0; r < 4; ++r)
                        if (kt2 + c * 16 + quad * 4 + r > qg) sv[c][r] = -3e38f;
            }
            // tree max (dep depth 4)
            float mc[4];
            #pragma unroll
            for (int c = 0; c < 4; ++c)
                mc[c] = fmaxf(fmaxf(sv[c][0], sv[c][1]), fmaxf(sv[c][2], sv[c][3]));
            float m = fmaxf(fmaxf(mc[0], mc[1]), fmaxf(mc[2], mc[3]));
            m = fmaxf(m, __shfl_xor(m, 16, 64));
            m = fmaxf(m, __shfl_xor(m, 32, 64));

            // defer-max (T13): only rescale when the running max grew by >8
            if (__any(m > mi + 8.0f)) {
                const float mnew  = fmaxf(mi, m);
                const float alpha = exp2f(mi - mnew);
                mi = mnew;
                li *= alpha;
                #pragma unroll
                for (int r = 0; r < 4; ++r) {
                    const float ar = __shfl(alpha, quad * 4 + r, 64);
                    #pragma unroll
                    for (int dt = 0; dt < 4; ++dt) o[dt][r] *= ar;
                }
            }

            f16x4 ap[4];
            float rc[4];
            #pragma unroll
            for (int c = 0; c < 4; ++c) {
                const float p0 = exp2f(sv[c][0] - mi);
                const float p1 = exp2f(sv[c][1] - mi);
                const float p2 = exp2f(sv[c][2] - mi);
                const float p3 = exp2f(sv[c][3] - mi);
                rc[c] = (p0 + p1) + (p2 + p3);
                const f16x2 lo = cvt_pk(p0, p1);
                const f16x2 hi = cvt_pk(p2, p3);
                ap[c][0] = lo[0]; ap[c][1] = lo[1]; ap[c][2] = hi[0]; ap[c][3] = hi[1];
            }
            float rs = (rc[0] + rc[1]) + (rc[2] + rc[3]);
            rs += __shfl_xor(rs, 16, 64);
            rs += __shfl_xor(rs, 32, 64);
            li += rs;

            // O += P V : P^T C-layout IS the 16x16x16 A-frag (lane: q=lrow,
            // key=quad*4+j). V B-frag from Vs[d][key]: b64 per (dt,c).
            __builtin_amdgcn_s_setprio(1);
            #pragma unroll
            for (int dt = 0; dt < 4; ++dt)
                #pragma unroll
                for (int c = 0; c < 4; ++c) {
                    f16x4 vb = *(const f16x4*)&Vs[cur][(dt * 16 + lrow) * 72 + c * 16 + quad * 4];
                    o[dt] = MFMA16(ap[c], vb, o[dt]);
                }
            __builtin_amdgcn_s_setprio(0);
        }

        // publish tile i+1 into the other buffer; prefetch tile i+2
        if (i < 33) {
            const int nxt = cur ^ 1;
            *(uint4*)&Ks[nxt][ur * 72 + uc] = kr;
            *(uint4*)&Vs[nxt][ur * 72 + uc] = vr;
            if (i < 32) {
                const int ni  = i + 2;
                const int nkt = (ni < itA) ? ni : ni - itA;
                const int nb  = nkt * 64;
                kr = *(const uint4*)&kbase[(size_t)(nb + ur) * DD + uc];
                vr = *(const uint4*)&vbase[(size_t)ur * TT + nb + uc];
            }
        }
        __syncthreads();
    }

    // final writeout (phase B)
    #pragma unroll
    for (int r = 0; r < 4; ++r) {
        const float inv = 1.0f / __shfl(li, quad * 4 + r, 64);
        const int t = q0w + quad * 4 + r;
        #pragma unroll
        for (int dt = 0; dt < 4; ++dt)
            yh[((size_t)b * TT + t) * CC + h * 64 + dt * 16 + lrow] =
                f2h(o[dt][r] * inv);
    }
}

// ---------------------------------------------------------------------------
// ws layout (halves): qh | kh | vh (8.39M each) | xh 8.39M (yh aliases xh)
//                     | wat 3.15M | wpt 1.05M     ~ 75 MB
// ---------------------------------------------------------------------------
extern "C" void kernel_launch(void* const* d_in, const int* in_sizes, int n_in,
                              void* d_out, int out_size, void* d_ws, size_t ws_size,
                              hipStream_t stream) {
    const float* x      = (const float*)d_in[0];
    const float* w_attn = (const float*)d_in[1];
    const float* b_attn = (const float*)d_in[2];
    const float* w_proj = (const float*)d_in[3];
    const float* b_proj = (const float*)d_in[4];
    float* out = (float*)d_out;

    const size_t per = (size_t)BB * HH * TT * DD;      // 8,388,608
    ushort_t* qh  = (ushort_t*)d_ws;
    ushort_t* kh  = qh + per;
    ushort_t* vh  = kh + per;
    ushort_t* xh  = vh + per;
    ushort_t* yh  = xh;                                 // alias: xh dead after GEMM1
    ushort_t* wat = xh + (size_t)MM * CC;
    ushort_t* wpt = wat + (size_t)3 * CC * CC;

    cvt4_kernel<<<(MM * CC / 4 + 255) / 256, 256, 0, stream>>>(x, xh, MM * CC / 4);
    // both weight transposes in one launch: bx<96 -> w_attn, else w_proj
    trcvt2_kernel<<<dim3(128, 32), 256, 0, stream>>>(w_attn, w_proj, wat, wpt);

    // GEMM1: 256x256 fine-phase kernel, grid 384, 96KB dyn LDS
    hgemm8_kernel<<<dim3(384), 512, 98304, stream>>>(
        xh, wat, b_attn, qh, kh, vh);

    // 8 balanced 128-row q-tile pairs (x) x 64 heads (y); 512 blocks of 8
    // waves, exactly 2/CU, all co-resident
    attn_mfma_kernel<<<dim3(8, BB * HH), 512, 0, stream>>>(qh, kh, vh, yh);

    hgemm_kernel<CC><<<dim3(CC / 128, MM / 128), 256, 0, stream>>>(
        yh, wpt, b_proj, out);
}